// Round 1
// baseline (363.026 us; speedup 1.0000x reference)
//
#include <hip/hip_runtime.h>
#include <hip/hip_fp16.h>

#define M_DIM 16384
#define K_DIM 2048
#define N_DIM 2048

#define BM 128
#define BN 128
#define BK 64

typedef int int4v  __attribute__((ext_vector_type(4)));
typedef int int16v __attribute__((ext_vector_type(16)));

__device__ __forceinline__ void gl_lds16(const void* g, void* l) {
    __builtin_amdgcn_global_load_lds(
        (const __attribute__((address_space(1))) void*)g,
        (__attribute__((address_space(3))) void*)l,
        16, 0, 0);
}

__device__ __forceinline__ int pack4(int4v v) {
    return (v[0] & 255) | ((v[1] & 255) << 8) | ((v[2] & 255) << 16) | (v[3] << 24);
}

// x: int32 [M,K] -> int8 [M,K], 16 elements per thread
__global__ void pack_x_kernel(const int* __restrict__ x, char* __restrict__ xp) {
    int i = blockIdx.x * 256 + threadIdx.x;
    const int4v* src = (const int4v*)x;
    int4v a = src[i * 4 + 0];
    int4v b = src[i * 4 + 1];
    int4v c = src[i * 4 + 2];
    int4v d = src[i * 4 + 3];
    int4v o;
    o[0] = pack4(a); o[1] = pack4(b); o[2] = pack4(c); o[3] = pack4(d);
    ((int4v*)xp)[i] = o;
}

// weight: int32 [K,N] -> int8 WT [N,K] (transpose + pack), 64x64 tiles via LDS
__global__ void wt_pack_kernel(const int* __restrict__ w, char* __restrict__ wt) {
    __shared__ char tile[64][68];   // [k][n], padded pitch
    int b  = blockIdx.x;            // 32 (k) x 32 (n) tiles
    int k0 = (b & 31) * 64;
    int n0 = (b >> 5) * 64;
    int t  = threadIdx.x;           // 256
    int r  = t >> 2;                // 0..63
    int c  = (t & 3) * 16;          // 0,16,32,48

    // phase 1: load w[k0+r][n0+c .. +16] (16 ints), pack to 16 bytes, store row-wise
    const int* src = w + (size_t)(k0 + r) * N_DIM + n0 + c;
    int4v a = *(const int4v*)(src + 0);
    int4v bb = *(const int4v*)(src + 4);
    int4v cc = *(const int4v*)(src + 8);
    int4v dd = *(const int4v*)(src + 12);
    *(int*)&tile[r][c + 0]  = pack4(a);
    *(int*)&tile[r][c + 4]  = pack4(bb);
    *(int*)&tile[r][c + 8]  = pack4(cc);
    *(int*)&tile[r][c + 12] = pack4(dd);
    __syncthreads();

    // phase 2: gather column r (n = n0+r), k chunk c -> 16B store
    char buf[16];
#pragma unroll
    for (int j = 0; j < 16; ++j) buf[j] = tile[c + j][r];
    *(int4v*)(wt + (size_t)(n0 + r) * K_DIM + k0 + c) = *(int4v*)buf;
}

// GEMM: A int8 [M,K], BT int8 [N,K]  ->  C fp32 [M,N] (+bias)
// block = 256 threads = 4 waves; 128x128 tile; BK=64; each wave does 2x2 of 32x32 MFMA tiles.
// LDS slot layout (16B slots): slot s = ((mb*2 + ks)*2 + kh)*32 + r
//   holds X[mb*32 + r][k0 + ks*32 + kh*16 .. +16]  (X = A rows or BT rows)
// => fragment read for (mb, ks) is exactly slot (mb*2+ks)*64 + lane  (lane-linear, conflict-free)
// => staging is slot-linear so global_load_lds (wave base + lane*16) works directly.
__global__ void gemm_i8_kernel(const char* __restrict__ A, const char* __restrict__ BT,
                               const __half* __restrict__ bias, float* __restrict__ C) {
    __shared__ char Asm[BM * BK];   // 8192 B = 512 slots
    __shared__ char Bsm[BN * BK];   // 8192 B

    int bid = blockIdx.x;
    int mt = bid & 127;             // M/BM = 128, m fastest (blocks sharing B-tile adjacent)
    int nt = bid >> 7;              // N/BN = 16
    int R0 = mt * BM, C0 = nt * BN;

    int t = threadIdx.x;
    int lane = t & 63;
    int w = t >> 6;
    int wm = w & 1, wn = w >> 1;    // wave quadrant (64x64)

    int16v acc[2][2];
#pragma unroll
    for (int i = 0; i < 2; ++i)
#pragma unroll
        for (int j = 0; j < 2; ++j) acc[i][j] = (int16v)0;

    // precompute staging slot decompositions for this thread's two slots
    int s0 = t, s1 = t + 256;
    int r5_0 = s0 & 31, kh0 = (s0 >> 5) & 1, ks0 = (s0 >> 6) & 1, mb0 = s0 >> 7;
    int r5_1 = s1 & 31, kh1 = (s1 >> 5) & 1, ks1 = (s1 >> 6) & 1, mb1 = s1 >> 7;
    size_t aoff0 = (size_t)(R0 + mb0 * 32 + r5_0) * K_DIM + (ks0 * 32 + kh0 * 16);
    size_t aoff1 = (size_t)(R0 + mb1 * 32 + r5_1) * K_DIM + (ks1 * 32 + kh1 * 16);
    size_t boff0 = (size_t)(C0 + mb0 * 32 + r5_0) * K_DIM + (ks0 * 32 + kh0 * 16);
    size_t boff1 = (size_t)(C0 + mb1 * 32 + r5_1) * K_DIM + (ks1 * 32 + kh1 * 16);

    for (int it = 0; it < K_DIM / BK; ++it) {
        int k0 = it * BK;
        gl_lds16(A + aoff0 + k0, &Asm[s0 * 16]);
        gl_lds16(A + aoff1 + k0, &Asm[s1 * 16]);
        gl_lds16(BT + boff0 + k0, &Bsm[s0 * 16]);
        gl_lds16(BT + boff1 + k0, &Bsm[s1 * 16]);
        __syncthreads();   // drains vmcnt (global_load_lds) before reads

#pragma unroll
        for (int ks = 0; ks < 2; ++ks) {
            int4v af[2], bf[2];
#pragma unroll
            for (int i = 0; i < 2; ++i)
                af[i] = *(const int4v*)&Asm[(((wm * 2 + i) * 2 + ks) * 64 + lane) * 16];
#pragma unroll
            for (int j = 0; j < 2; ++j)
                bf[j] = *(const int4v*)&Bsm[(((wn * 2 + j) * 2 + ks) * 64 + lane) * 16];
#pragma unroll
            for (int i = 0; i < 2; ++i)
#pragma unroll
                for (int j = 0; j < 2; ++j)
                    acc[i][j] = __builtin_amdgcn_mfma_i32_32x32x32_i8(af[i], bf[j], acc[i][j], 0, 0, 0);
        }
        __syncthreads();   // compute done before next stage overwrites
    }

    // epilogue: C/D layout col=lane&31, row=(reg&3)+8*(reg>>2)+4*(lane>>5)
    int col = lane & 31;
    int rbase = (lane >> 5) * 4;
#pragma unroll
    for (int j = 0; j < 2; ++j) {
        int cn = C0 + wn * 64 + j * 32 + col;
        float bv = __half2float(bias[cn]);
#pragma unroll
        for (int i = 0; i < 2; ++i) {
            int rm = R0 + wm * 64 + i * 32 + rbase;
#pragma unroll
            for (int reg = 0; reg < 16; ++reg) {
                int row = rm + (reg & 3) + 8 * (reg >> 2);
                C[(size_t)row * N_DIM + cn] = (float)acc[i][j][reg] + bv;
            }
        }
    }
}

extern "C" void kernel_launch(void* const* d_in, const int* in_sizes, int n_in,
                              void* d_out, int out_size, void* d_ws, size_t ws_size,
                              hipStream_t stream) {
    const int* x = (const int*)d_in[0];        // int8 values stored as int32
    const int* wgt = (const int*)d_in[1];      // int8 values stored as int32
    const __half* bias = (const __half*)d_in[2];
    float* out = (float*)d_out;

    char* xp = (char*)d_ws;                                   // 32 MiB packed A
    char* wt = (char*)d_ws + (size_t)M_DIM * K_DIM;           // 4 MiB packed W^T

    pack_x_kernel<<<(M_DIM * (size_t)K_DIM) / 16 / 256, 256, 0, stream>>>(x, xp);
    wt_pack_kernel<<<(K_DIM / 64) * (N_DIM / 64), 256, 0, stream>>>(wgt, wt);
    gemm_i8_kernel<<<(M_DIM / BM) * (N_DIM / BN), 256, 0, stream>>>(xp, wt, bias, out);
}

// Round 2
// 362.966 us; speedup vs baseline: 1.0002x; 1.0002x over previous
//
#include <hip/hip_runtime.h>
#include <hip/hip_fp16.h>

#define M_DIM 16384
#define K_DIM 2048
#define N_DIM 2048

#define BM 128
#define BN 128
#define BK 128

typedef int int4v  __attribute__((ext_vector_type(4)));
typedef int int16v __attribute__((ext_vector_type(16)));

__device__ __forceinline__ void gl_lds16(const void* g, void* l) {
    __builtin_amdgcn_global_load_lds(
        (const __attribute__((address_space(1))) void*)g,
        (__attribute__((address_space(3))) void*)l,
        16, 0, 0);
}

__device__ __forceinline__ int pack4(int4v v) {
    return (v[0] & 255) | ((v[1] & 255) << 8) | ((v[2] & 255) << 16) | (v[3] << 24);
}

// x: int32 [M,K] -> int8 [M,K]
// Lane-contiguous: thread t loads src[base + t] (16B/lane coalesced), stores one
// packed int (4B/lane coalesced). 4 chunks per thread, stride 256.
__global__ void pack_x_kernel(const int* __restrict__ x, char* __restrict__ xp) {
    const int4v* src = (const int4v*)x;
    int* dst = (int*)xp;
    int base = blockIdx.x * 1024 + threadIdx.x;
#pragma unroll
    for (int j = 0; j < 4; ++j) {
        int i = base + j * 256;
        dst[i] = pack4(src[i]);
    }
}

// weight: int32 [K,N] -> int8 WT [N,K] (transpose + pack), 64x64 tiles via LDS
__global__ void wt_pack_kernel(const int* __restrict__ w, char* __restrict__ wt) {
    __shared__ char tile[64][68];   // [k][n], padded pitch
    int b  = blockIdx.x;            // 32 (k) x 32 (n) tiles
    int k0 = (b & 31) * 64;
    int n0 = (b >> 5) * 64;
    int t  = threadIdx.x;           // 256
    int r  = t >> 2;                // 0..63
    int c  = (t & 3) * 16;          // 0,16,32,48

    const int* src = w + (size_t)(k0 + r) * N_DIM + n0 + c;
    int4v a = *(const int4v*)(src + 0);
    int4v bb = *(const int4v*)(src + 4);
    int4v cc = *(const int4v*)(src + 8);
    int4v dd = *(const int4v*)(src + 12);
    *(int*)&tile[r][c + 0]  = pack4(a);
    *(int*)&tile[r][c + 4]  = pack4(bb);
    *(int*)&tile[r][c + 8]  = pack4(cc);
    *(int*)&tile[r][c + 12] = pack4(dd);
    __syncthreads();

    char buf[16];
#pragma unroll
    for (int j = 0; j < 16; ++j) buf[j] = tile[c + j][r];
    *(int4v*)(wt + (size_t)(n0 + r) * K_DIM + k0 + c) = *(int4v*)buf;
}

// GEMM: A int8 [M,K], BT int8 [N,K]  ->  C fp32 [M,N] (+bias)
// block = 256 threads = 4 waves; 128x128 tile; BK=128; each wave 2x2 of 32x32x32 MFMA.
// LDS slot layout (16B slots, 1024 slots/buffer):
//   slot s = ((mb*4 + ks)*2 + kh)*32 + r  holds X[mb*32+r][k0 + ks*32 + kh*16 ..+16]
// => fragment read (mb,ks): slot (mb*4+ks)*64 + lane  (lane-linear, conflict-free)
// => staging slot-linear so global_load_lds (wave base + lane*16) works directly.
__global__ void gemm_i8_kernel(const char* __restrict__ A, const char* __restrict__ BT,
                               const __half* __restrict__ bias, float* __restrict__ C) {
    __shared__ char Asm[BM * BK];   // 16384 B = 1024 slots
    __shared__ char Bsm[BN * BK];   // 16384 B

    int bid = blockIdx.x;
    int mt = bid & 127;             // M/BM = 128, m fastest
    int nt = bid >> 7;              // N/BN = 16
    int R0 = mt * BM, C0 = nt * BN;

    int t = threadIdx.x;
    int lane = t & 63;
    int w = t >> 6;
    int wm = w & 1, wn = w >> 1;    // wave quadrant (64x64)

    int16v acc[2][2];
#pragma unroll
    for (int i = 0; i < 2; ++i)
#pragma unroll
        for (int j = 0; j < 2; ++j) acc[i][j] = (int16v)0;

    // staging: thread t owns slots t + 256*j, j=0..3, for each of A and B
    size_t aoff[4], boff[4];
#pragma unroll
    for (int j = 0; j < 4; ++j) {
        int s = t + j * 256;
        int r5 = s & 31, kh = (s >> 5) & 1, ks = (s >> 6) & 3, mb = s >> 8;
        int kk = ks * 32 + kh * 16;
        aoff[j] = (size_t)(R0 + mb * 32 + r5) * K_DIM + kk;
        boff[j] = (size_t)(C0 + mb * 32 + r5) * K_DIM + kk;
    }

    for (int it = 0; it < K_DIM / BK; ++it) {
        int k0 = it * BK;
#pragma unroll
        for (int j = 0; j < 4; ++j) {
            gl_lds16(A + aoff[j] + k0, &Asm[(t + j * 256) * 16]);
            gl_lds16(BT + boff[j] + k0, &Bsm[(t + j * 256) * 16]);
        }
        __syncthreads();   // drains vmcnt before LDS reads

#pragma unroll
        for (int ks = 0; ks < 4; ++ks) {
            int4v af[2], bf[2];
#pragma unroll
            for (int i = 0; i < 2; ++i)
                af[i] = *(const int4v*)&Asm[(((wm * 2 + i) * 4 + ks) * 64 + lane) * 16];
#pragma unroll
            for (int j = 0; j < 2; ++j)
                bf[j] = *(const int4v*)&Bsm[(((wn * 2 + j) * 4 + ks) * 64 + lane) * 16];
#pragma unroll
            for (int i = 0; i < 2; ++i)
#pragma unroll
                for (int j = 0; j < 2; ++j)
                    acc[i][j] = __builtin_amdgcn_mfma_i32_32x32x32_i8(af[i], bf[j], acc[i][j], 0, 0, 0);
        }
        __syncthreads();   // compute done before next stage overwrites
    }

    // epilogue: C/D layout col=lane&31, row=(reg&3)+8*(reg>>2)+4*(lane>>5)
    int col = lane & 31;
    int rbase = (lane >> 5) * 4;
#pragma unroll
    for (int j = 0; j < 2; ++j) {
        int cn = C0 + wn * 64 + j * 32 + col;
        float bv = __half2float(bias[cn]);
#pragma unroll
        for (int i = 0; i < 2; ++i) {
            int rm = R0 + wm * 64 + i * 32 + rbase;
#pragma unroll
            for (int reg = 0; reg < 16; ++reg) {
                int row = rm + (reg & 3) + 8 * (reg >> 2);
                C[(size_t)row * N_DIM + cn] = (float)acc[i][j][reg] + bv;
            }
        }
    }
}

extern "C" void kernel_launch(void* const* d_in, const int* in_sizes, int n_in,
                              void* d_out, int out_size, void* d_ws, size_t ws_size,
                              hipStream_t stream) {
    const int* x = (const int*)d_in[0];        // int8 values stored as int32
    const int* wgt = (const int*)d_in[1];      // int8 values stored as int32
    const __half* bias = (const __half*)d_in[2];
    float* out = (float*)d_out;

    char* xp = (char*)d_ws;                                   // 32 MiB packed A
    char* wt = (char*)d_ws + (size_t)M_DIM * K_DIM;           // 4 MiB packed W^T

    pack_x_kernel<<<(M_DIM * (size_t)K_DIM) / 4 / 1024, 256, 0, stream>>>(x, xp);
    wt_pack_kernel<<<(K_DIM / 64) * (N_DIM / 64), 256, 0, stream>>>(wgt, wt);
    gemm_i8_kernel<<<(M_DIM / BM) * (N_DIM / BN), 256, 0, stream>>>(xp, wt, bias, out);
}

// Round 3
// 314.233 us; speedup vs baseline: 1.1553x; 1.1551x over previous
//
#include <hip/hip_runtime.h>
#include <hip/hip_fp16.h>

#define M_DIM 16384
#define K_DIM 2048
#define N_DIM 2048

#define BM 128
#define BN 128
#define BK 128

typedef int int4v  __attribute__((ext_vector_type(4)));
typedef int int16v __attribute__((ext_vector_type(16)));

__device__ __forceinline__ void gl_lds16(const void* g, void* l) {
    __builtin_amdgcn_global_load_lds(
        (const __attribute__((address_space(1))) void*)g,
        (__attribute__((address_space(3))) void*)l,
        16, 0, 0);
}

__device__ __forceinline__ int pack4(int4v v) {
    return (v[0] & 255) | ((v[1] & 255) << 8) | ((v[2] & 255) << 16) | (v[3] << 24);
}

// x: int32 [M,K] -> int8 [M,K]; lane-contiguous loads/stores
__global__ void pack_x_kernel(const int* __restrict__ x, char* __restrict__ xp) {
    const int4v* src = (const int4v*)x;
    int* dst = (int*)xp;
    int base = blockIdx.x * 1024 + threadIdx.x;
#pragma unroll
    for (int j = 0; j < 4; ++j) {
        int i = base + j * 256;
        dst[i] = pack4(src[i]);
    }
}

// weight: int32 [K,N] -> int8 WT [N,K] (transpose + pack), 64x64 tiles via LDS
__global__ void wt_pack_kernel(const int* __restrict__ w, char* __restrict__ wt) {
    __shared__ char tile[64][68];
    int b  = blockIdx.x;
    int k0 = (b & 31) * 64;
    int n0 = (b >> 5) * 64;
    int t  = threadIdx.x;
    int r  = t >> 2;
    int c  = (t & 3) * 16;

    const int* src = w + (size_t)(k0 + r) * N_DIM + n0 + c;
    int4v a = *(const int4v*)(src + 0);
    int4v bb = *(const int4v*)(src + 4);
    int4v cc = *(const int4v*)(src + 8);
    int4v dd = *(const int4v*)(src + 12);
    *(int*)&tile[r][c + 0]  = pack4(a);
    *(int*)&tile[r][c + 4]  = pack4(bb);
    *(int*)&tile[r][c + 8]  = pack4(cc);
    *(int*)&tile[r][c + 12] = pack4(dd);
    __syncthreads();

    char buf[16];
#pragma unroll
    for (int j = 0; j < 16; ++j) buf[j] = tile[c + j][r];
    *(int4v*)(wt + (size_t)(n0 + r) * K_DIM + k0 + c) = *(int4v*)buf;
}

// GEMM: A int8 [M,K], BT int8 [N,K] -> C fp32 [M,N] (+bias)
// 256 thr = 4 waves; 128x128 tile; BK=128; wave = 2x2 of 32x32x32 i8 MFMA.
// LDS layout (16B slots, 1024/buffer), XOR-swizzled row-major:
//   slot s = r*8 + c  holds  X[r][k0 + (c ^ (r&7))*16 .. +16]
// Staging (slot-linear, 8 lanes/row): each gl_lds16 instr reads 8 rows x 128
// contiguous bytes (chunk-permuted) -> 16 fully-used cache lines / instr.
// Fragment read (row base mult. of 32): slot = row*8 + ((2*ks + (l>>5)) ^ (l&7))
// -> slot%8 distinct across each 8-lane group -> all 32 banks covered, conflict-free.
__global__ void gemm_i8_kernel(const char* __restrict__ A, const char* __restrict__ BT,
                               const __half* __restrict__ bias, float* __restrict__ C) {
    __shared__ char Asm[BM * BK];   // 16384 B
    __shared__ char Bsm[BN * BK];   // 16384 B

    int bid = blockIdx.x;
    int mt = bid & 127;             // m fastest
    int nt = bid >> 7;
    int R0 = mt * BM, C0 = nt * BN;

    int t = threadIdx.x;
    int lane = t & 63;
    int w = t >> 6;
    int wm = w & 1, wn = w >> 1;

    int16v acc[2][2];
#pragma unroll
    for (int i = 0; i < 2; ++i)
#pragma unroll
        for (int j = 0; j < 2; ++j) acc[i][j] = (int16v)0;

    // staging: thread t owns slots t + 256*j; slot s -> row s>>3, stored chunk (s&7)^(row&7)
    size_t aoff[4], boff[4];
#pragma unroll
    for (int j = 0; j < 4; ++j) {
        int s = t + j * 256;
        int r = s >> 3;
        int cg = (s & 7) ^ (r & 7);
        aoff[j] = (size_t)(R0 + r) * K_DIM + cg * 16;
        boff[j] = (size_t)(C0 + r) * K_DIM + cg * 16;
    }

    int l31 = lane & 31, l7 = lane & 7, khl = lane >> 5;
    // fragment slot bases (row*8), row = quad*32 + l31
    int arow[2], brow[2];
#pragma unroll
    for (int i = 0; i < 2; ++i) arow[i] = (wm * 64 + i * 32 + l31) * 8;
#pragma unroll
    for (int j = 0; j < 2; ++j) brow[j] = (wn * 64 + j * 32 + l31) * 8;

    for (int it = 0; it < K_DIM / BK; ++it) {
        int k0 = it * BK;
#pragma unroll
        for (int j = 0; j < 4; ++j) {
            gl_lds16(A + aoff[j] + k0, &Asm[(t + j * 256) * 16]);
            gl_lds16(BT + boff[j] + k0, &Bsm[(t + j * 256) * 16]);
        }
        __syncthreads();

#pragma unroll
        for (int ks = 0; ks < 4; ++ks) {
            int sw0 = (2 * ks + khl) ^ l7;   // swizzled chunk for this lane
            int4v af[2], bf[2];
#pragma unroll
            for (int i = 0; i < 2; ++i)
                af[i] = *(const int4v*)&Asm[(arow[i] + sw0) * 16];
#pragma unroll
            for (int j = 0; j < 2; ++j)
                bf[j] = *(const int4v*)&Bsm[(brow[j] + sw0) * 16];
#pragma unroll
            for (int i = 0; i < 2; ++i)
#pragma unroll
                for (int j = 0; j < 2; ++j)
                    acc[i][j] = __builtin_amdgcn_mfma_i32_32x32x32_i8(af[i], bf[j], acc[i][j], 0, 0, 0);
        }
        __syncthreads();
    }

    // epilogue: C/D layout col=lane&31, row=(reg&3)+8*(reg>>2)+4*(lane>>5)
    int col = lane & 31;
    int rbase = (lane >> 5) * 4;
#pragma unroll
    for (int j = 0; j < 2; ++j) {
        int cn = C0 + wn * 64 + j * 32 + col;
        float bv = __half2float(bias[cn]);
#pragma unroll
        for (int i = 0; i < 2; ++i) {
            int rm = R0 + wm * 64 + i * 32 + rbase;
#pragma unroll
            for (int reg = 0; reg < 16; ++reg) {
                int row = rm + (reg & 3) + 8 * (reg >> 2);
                C[(size_t)row * N_DIM + cn] = (float)acc[i][j][reg] + bv;
            }
        }
    }
}

extern "C" void kernel_launch(void* const* d_in, const int* in_sizes, int n_in,
                              void* d_out, int out_size, void* d_ws, size_t ws_size,
                              hipStream_t stream) {
    const int* x = (const int*)d_in[0];
    const int* wgt = (const int*)d_in[1];
    const __half* bias = (const __half*)d_in[2];
    float* out = (float*)d_out;

    char* xp = (char*)d_ws;                                   // 32 MiB packed A
    char* wt = (char*)d_ws + (size_t)M_DIM * K_DIM;           // 4 MiB packed W^T

    pack_x_kernel<<<(M_DIM * (size_t)K_DIM) / 4 / 1024, 256, 0, stream>>>(x, xp);
    wt_pack_kernel<<<(K_DIM / 64) * (N_DIM / 64), 256, 0, stream>>>(wgt, wt);
    gemm_i8_kernel<<<(M_DIM / BM) * (N_DIM / BN), 256, 0, stream>>>(xp, wt, bias, out);
}